// Round 25
// baseline (528.268 us; speedup 1.0000x reference)
//
#include <hip/hip_runtime.h>

typedef __attribute__((ext_vector_type(8))) short bf16x8;
typedef __attribute__((ext_vector_type(4))) float f32x4;

#define MFMA16(a, b, c) __builtin_amdgcn_mfma_f32_16x16x32_bf16((a), (b), (c), 0, 0, 0)

__device__ __forceinline__ float b2f(unsigned short u) {
  unsigned int v = ((unsigned int)u) << 16;
  return __builtin_bit_cast(float, v);
}
__device__ __forceinline__ unsigned short f2b(float f) {
  unsigned int u = __builtin_bit_cast(unsigned int, f);
  u += 0x7fffu + ((u >> 16) & 1u);
  return (unsigned short)(u >> 16);
}
__device__ __forceinline__ void gload16(const void* g, void* l) {
  __builtin_amdgcn_global_load_lds(
      (const __attribute__((address_space(1))) unsigned int*)g,
      (__attribute__((address_space(3))) unsigned int*)l, 16, 0, 0);
}

// ------- weight prep: z=0..2: w fp32 [a][b] -> bf16 [b][a]; z=3: wo copy-convert -------
__global__ __launch_bounds__(256) void k_wprep(
    const float* __restrict__ wq, const float* __restrict__ wk,
    const float* __restrict__ wv, const float* __restrict__ wo,
    unsigned short* __restrict__ outbase) {
  const int z = blockIdx.z;
  const int t = threadIdx.x;
  if (z == 3) {  // wo -> outbase+786432, layout preserved
    const int r0 = blockIdx.x << 6, s0 = blockIdx.y << 6;
    const int row = r0 + (t >> 2), col = s0 + (t & 3) * 16;
    const float* src = wo + (size_t)row * 512 + col;
    unsigned short* dst = outbase + 786432 + (size_t)row * 512 + col;
    unsigned short o[16];
#pragma unroll
    for (int i = 0; i < 4; ++i) {
      const float4 v = ((const float4*)src)[i];
      o[i * 4 + 0] = f2b(v.x); o[i * 4 + 1] = f2b(v.y);
      o[i * 4 + 2] = f2b(v.z); o[i * 4 + 3] = f2b(v.w);
    }
    *(uint4*)dst = *(const uint4*)&o[0];
    *(uint4*)(dst + 8) = *(const uint4*)&o[8];
    return;
  }
  __shared__ unsigned short tile[64][72];
  const float* in = (z == 0) ? wq : (z == 1) ? wk : wv;
  unsigned short* out = outbase + (size_t)z * 262144u;
  const int r0 = blockIdx.x << 6, s0 = blockIdx.y << 6;
  {
    const int sl = t >> 3, rl = (t & 7) << 3;
#pragma unroll
    for (int pass = 0; pass < 2; ++pass) {
      const int s = sl + pass * 32;
      const float* src = in + (size_t)(s0 + s) * 512 + r0 + rl;
      const float4 f0 = ((const float4*)src)[0];
      const float4 f1 = ((const float4*)src)[1];
      tile[rl + 0][s] = f2b(f0.x);
      tile[rl + 1][s] = f2b(f0.y);
      tile[rl + 2][s] = f2b(f0.z);
      tile[rl + 3][s] = f2b(f0.w);
      tile[rl + 4][s] = f2b(f1.x);
      tile[rl + 5][s] = f2b(f1.y);
      tile[rl + 6][s] = f2b(f1.z);
      tile[rl + 7][s] = f2b(f1.w);
    }
  }
  __syncthreads();
  {
    const int rl = t >> 3, sl = (t & 7) << 3;
#pragma unroll
    for (int pass = 0; pass < 2; ++pass) {
      const int r = rl + pass * 32;
      uint4 v = *(const uint4*)&tile[r][sl];
      *(uint4*)(out + (size_t)(r0 + r) * 512 + s0 + sl) = v;
    }
  }
}

// ---- fused bias prep: blocks 0-1: bvo[o]=bo[o]+wo[o][:]*bv; blocks 2-3: u[c]=bq^T wk[:][c]
__global__ __launch_bounds__(256) void k_bias(
    const float* __restrict__ wo, const float* __restrict__ bv,
    const float* __restrict__ bo, const float* __restrict__ wk,
    const float* __restrict__ bq, float* __restrict__ bvo,
    float* __restrict__ u) {
  const int bid = blockIdx.x;
  if (bid < 2) {
    const int o = bid * 256 + threadIdx.x;
    float acc = bo[o];
    const float* row = wo + (size_t)o * 512;
    for (int j = 0; j < 512; ++j) acc += row[j] * bv[j];
    bvo[o] = acc;
  } else {
    const int c = (bid - 2) * 256 + threadIdx.x;
    float acc = 0.f;
    for (int o = 0; o < 512; ++o) acc += bq[o] * wk[(size_t)o * 512 + c];
    u[c] = acc;
  }
}

// ---- K0: transpose via global_load_lds (best of 6 variants; closed). ----
__global__ __launch_bounds__(256, 4) void k_transpose(
    const float* __restrict__ X, unsigned short* __restrict__ XT,
    unsigned short* __restrict__ XV) {
  __shared__ float lds[2][8 * 516];
  const int hz = blockIdx.x;
  const int cgB = blockIdx.y;
  const int b = blockIdx.z;
  const int h0 = hz << 2;
  const int c0 = cgB << 5;
  const int t = threadIdx.x;
  const float* xb = X + (size_t)b * 8388608u + (size_t)h0 * 128;

  auto stage = [&](int s) {
    float* dstb = lds[s & 1];
#pragma unroll
    for (int i = 0; i < 4; ++i) {
      const int q4 = i * 256 + t;
      const int cl = q4 >> 7;
      const int q = q4 & 127;
      gload16(xb + (size_t)(c0 + s * 8 + cl) * 16384 + q * 4,
              dstb + (size_t)cl * 516 + q * 4);
    }
  };

  unsigned short xo[2][32];

  stage(0);
#pragma unroll
  for (int s = 0; s < 4; ++s) {
    if (s < 3) {
      stage(s + 1);
      asm volatile("s_waitcnt vmcnt(4)" ::: "memory");
    } else {
      asm volatile("s_waitcnt vmcnt(0)" ::: "memory");
    }
    __builtin_amdgcn_s_barrier();
    const float* L = lds[s & 1];
#pragma unroll
    for (int pp = 0; pp < 2; ++pp) {
      const int p = t + pp * 256;
#pragma unroll
      for (int cl = 0; cl < 8; ++cl)
        xo[pp][s * 8 + cl] = f2b(L[cl * 516 + p]);
    }
    {
      const int cl = t >> 5, win = t & 15, hb = (t >> 4) & 1;
      const int wing = b * 256 + (h0 >> 3) * 16 + win;
      const int tok0 = (h0 & 4) * 8;
      unsigned short* dvb =
          XV + (size_t)(c0 + s * 8 + cl) * 131072 + (size_t)wing * 64 + tok0;
#pragma unroll
      for (int k = 0; k < 2; ++k) {
        const int hr = hb + k * 2;
        const float* src = &L[cl * 516 + hr * 128 + win * 8];
        unsigned short ov[8];
#pragma unroll
        for (int j = 0; j < 8; ++j) ov[j] = f2b(src[j]);
        *(uint4*)(dvb + hr * 8) = *(const uint4*)ov;
      }
    }
    __builtin_amdgcn_s_barrier();
  }

#pragma unroll
  for (int pp = 0; pp < 2; ++pp) {
    const int p = t + pp * 256;
    unsigned short* d =
        XT + ((size_t)b * 16384 + (size_t)h0 * 128 + p) * 512 + c0;
    *(uint4*)(d + 0) = *(const uint4*)&xo[pp][0];
    *(uint4*)(d + 8) = *(const uint4*)&xo[pp][8];
    *(uint4*)(d + 16) = *(const uint4*)&xo[pp][16];
    *(uint4*)(d + 24) = *(const uint4*)&xo[pp][24];
  }
}

// ==== 256x256 GEMM, 16 K-subtiles of 32, 4-buffer depth-3 counted pipeline + swizzle
// (R21 structure — best measured).
// MODE 0: T-proj. A=xT, B=Bqk. bf16 C[m=pixel][n] ldc=512, bias0[n]. grid 1024.
// MODE 2: final.  A=Y(m=pixel), B=wvo(n=chan). fp32 out[b][cn][pix]; lane holds 4
//         consecutive PIXELS of one channel -> f32x4 NT stores (16 full 64B
//         lines per wave-instruction). bias0[cn]. grid 1024.
// MODE 4: fused weight-prep (grid 8).
template <int MODE>
__global__ __launch_bounds__(512, 2) void k_gemm256(
    const unsigned short* __restrict__ A, const unsigned short* __restrict__ B,
    const float* __restrict__ bias0, void* __restrict__ C0v) {
  __shared__ unsigned short lsA[4][256 * 32];
  __shared__ unsigned short lsB[4][256 * 32];
  const int bid = blockIdx.x;
  int mt, nt, sel = 0;
  if (MODE == 0 || MODE == 2) {
    const int work = ((bid & 7) << 7) + (bid >> 3);  // grid 1024
    mt = work >> 1; nt = work & 1;
  } else {  // MODE 4
    sel = bid >> 2;
    mt = bid & 1; nt = (bid >> 1) & 1;
  }
  const unsigned short* Ap = A;
  const unsigned short* Bp = B;
  if (MODE == 4) {
    Ap = sel ? A + 786432 : A + 262144;  // wo_b : wkT
    Bp = sel ? A + 524288 : A;           // wvT  : wqT
  }
  const int m0 = mt << 8, n0 = nt << 8;

  const int t = threadIdx.x;
  const int l = t & 63;
  const int lr = l & 15, lg = l >> 4;
  const int w = t >> 6;
  const int wr = w >> 2, wc = w & 3;
  const int ra = wr << 7, rb = wc << 6;
  const int srowS = t >> 2;            // 0..127 (+128 for 2nd gload)
  const int scolS = (t & 3) << 3;      // shorts
  const int ssw = ((srowS >> 1) & 3) << 3;   // stage-side inverse swizzle
  const int scolX = scolS ^ ssw;             // swizzled global column
  const int rsw = (lr >> 1) & 3;             // read-side swizzle
  const int rco = (lg ^ rsw) * 8;            // read column offset (shorts)

  f32x4 acc[8][4];
#pragma unroll
  for (int i = 0; i < 8; ++i)
#pragma unroll
    for (int j = 0; j < 4; ++j) acc[i][j] = f32x4{0.f, 0.f, 0.f, 0.f};

  auto stage = [&](int kt) {
    const int buf = kt & 3, k0 = kt << 5;
#pragma unroll
    for (int hh = 0; hh < 2; ++hh) {
      gload16(Ap + (size_t)(m0 + srowS + hh * 128) * 512 + k0 + scolX,
              &lsA[buf][(srowS + hh * 128) * 32 + scolS]);
      gload16(Bp + (size_t)(n0 + srowS + hh * 128) * 512 + k0 + scolX,
              &lsB[buf][(srowS + hh * 128) * 32 + scolS]);
    }
  };
  auto compute = [&](int kt) {
    const int buf = kt & 3;
    bf16x8 af[8], bfv[4];
#pragma unroll
    for (int i = 0; i < 8; ++i)
      af[i] = *(const bf16x8*)&lsA[buf][(ra + i * 16 + lr) * 32 + rco];
#pragma unroll
    for (int j = 0; j < 4; ++j)
      bfv[j] = *(const bf16x8*)&lsB[buf][(rb + j * 16 + lr) * 32 + rco];
    __builtin_amdgcn_s_setprio(1);
#pragma unroll
    for (int i = 0; i < 8; ++i)
#pragma unroll
      for (int j = 0; j < 4; ++j)
        acc[i][j] = MFMA16(af[i], bfv[j], acc[i][j]);
    __builtin_amdgcn_s_setprio(0);
  };

  stage(0); stage(1); stage(2);  // depth-3 prologue

#define GITER(kt, vm)                                        \
  asm volatile("s_waitcnt vmcnt(" #vm ")" ::: "memory");     \
  __builtin_amdgcn_s_barrier();                              \
  __builtin_amdgcn_sched_barrier(0);                         \
  if ((kt) + 3 < 16) stage((kt) + 3);                        \
  compute(kt);                                               \
  __builtin_amdgcn_sched_barrier(0);                         \
  __builtin_amdgcn_s_barrier();

  GITER(0, 8)  GITER(1, 8)  GITER(2, 8)  GITER(3, 8)
  GITER(4, 8)  GITER(5, 8)  GITER(6, 8)  GITER(7, 8)
  GITER(8, 8)  GITER(9, 8)  GITER(10, 8) GITER(11, 8)
  GITER(12, 8) GITER(13, 8) GITER(14, 4) GITER(15, 0)
#undef GITER

  // ---------------- epilogue ----------------
#pragma unroll
  for (int i = 0; i < 8; ++i) {
    const int cmb = m0 + ra + i * 16 + lg * 4;
#pragma unroll
    for (int j = 0; j < 4; ++j) {
      const int cn = n0 + rb + j * 16 + lr;
      if (MODE == 2) {
        // 4 consecutive pixels (cmb..cmb+3) of channel cn -> one f32x4 NT store
        const float bn = bias0[cn];
        f32x4 v4;
        v4[0] = acc[i][j][0] + bn;
        v4[1] = acc[i][j][1] + bn;
        v4[2] = acc[i][j][2] + bn;
        v4[3] = acc[i][j][3] + bn;
        const int bb = cmb >> 14, p = cmb & 16383;
        __builtin_nontemporal_store(
            v4, (f32x4*)((float*)C0v + (size_t)bb * 8388608 +
                         (size_t)cn * 16384 + p));
      } else {
        const float bn = (MODE == 0) ? bias0[cn] : 0.f;
#pragma unroll
        for (int r = 0; r < 4; ++r) {
          const int cm = cmb + r;
          if (MODE == 0) {
            ((unsigned short*)C0v)[(size_t)cm * 512 + cn] =
                f2b(acc[i][j][r] + bn);
          } else {
            unsigned short* Cs =
                (unsigned short*)C0v + (sel ? 1048576 : 1572864);
            Cs[(size_t)cm * 512 + cn] = f2b(acc[i][j][r]);
          }
        }
      }
    }
  }
}

// ---------------- K2: window attention, ONE WAVE PER WINDOW (unchanged) ----------------
__global__ __launch_bounds__(256) void k_attn(
    const unsigned short* __restrict__ Q, const unsigned short* __restrict__ XT,
    const unsigned short* __restrict__ XV, unsigned short* __restrict__ Y) {
  __shared__ unsigned short P_lds[4][64][72];
  const int t = threadIdx.x, w = t >> 6, l = t & 63;
  const int lr = l & 15, lg = l >> 4;
  const int grp = ((blockIdx.x & 7) << 6) + (blockIdx.x >> 3);  // 0..511
  const int win = grp * 4 + w;
  const int b = win >> 8, th = (win >> 4) & 15, tw = win & 15;
  const size_t p_base = (size_t)b * 16384 + (size_t)th * 1024 + (size_t)tw * 8;
  const size_t rowpix = p_base + (size_t)(lr >> 3) * 128 + (lr & 7);
  const unsigned short* qbase = Q + rowpix * 512;
  const unsigned short* kbase = XT + rowpix * 512;

  f32x4 acc[4][4];
#pragma unroll
  for (int i = 0; i < 4; ++i)
#pragma unroll
    for (int j = 0; j < 4; ++j) acc[i][j] = f32x4{0.f, 0.f, 0.f, 0.f};

  bf16x8 kp[2][4], qp[2][4];
#pragma unroll
  for (int pp = 0; pp < 2; ++pp) {
    const int co = pp * 32 + lg * 8;
#pragma unroll
    for (int i = 0; i < 4; ++i) {
      kp[pp][i] = *(const bf16x8*)(kbase + (size_t)i * 131072 + co);
      qp[pp][i] = *(const bf16x8*)(qbase + (size_t)i * 131072 + co);
    }
  }
#pragma unroll
  for (int cs = 0; cs < 16; ++cs) {
    const int cb = cs & 1;
    __builtin_amdgcn_s_setprio(1);
#pragma unroll
    for (int mt = 0; mt < 4; ++mt)
#pragma unroll
      for (int qt = 0; qt < 4; ++qt)
        acc[mt][qt] = MFMA16(kp[cb][mt], qp[cb][qt], acc[mt][qt]);
    __builtin_amdgcn_s_setprio(0);
    if (cs + 2 < 16) {
      const int co = (cs + 2) * 32 + lg * 8;
#pragma unroll
      for (int i = 0; i < 4; ++i) {
        kp[cb][i] = *(const bf16x8*)(kbase + (size_t)i * 131072 + co);
        qp[cb][i] = *(const bf16x8*)(qbase + (size_t)i * 131072 + co);
      }
    }
  }

  const float scale = 0.044194173824159216f;  // 1/sqrt(512)
#pragma unroll
  for (int qt = 0; qt < 4; ++qt) {
    float pv[4][4];
    float mx = -3.0e38f;
#pragma unroll
    for (int mt = 0; mt < 4; ++mt)
#pragma unroll
      for (int j = 0; j < 4; ++j) {
        const float s = acc[mt][qt][j] * scale;
        pv[mt][j] = s;
        mx = fmaxf(mx, s);
      }
    mx = fmaxf(mx, __shfl_xor(mx, 16));
    mx = fmaxf(mx, __shfl_xor(mx, 32));
    float sum = 0.f;
#pragma unroll
    for (int mt = 0; mt < 4; ++mt)
#pragma unroll
      for (int j = 0; j < 4; ++j) {
        const float e = __expf(pv[mt][j] - mx);
        pv[mt][j] = e;
        sum += e;
      }
    sum += __shfl_xor(sum, 16);
    sum += __shfl_xor(sum, 32);
    const float inv = 1.f / sum;
#pragma unroll
    for (int mt = 0; mt < 4; ++mt)
#pragma unroll
      for (int j = 0; j < 4; j += 2) {
        const unsigned int pk =
            (unsigned int)f2b(pv[mt][j] * inv) |
            ((unsigned int)f2b(pv[mt][j + 1] * inv) << 16);
        *(unsigned int*)&P_lds[w][qt * 16 + lr][mt * 16 + lg * 4 + j] = pk;
      }
  }

  bf16x8 pa0[4], pa1[4];
#pragma unroll
  for (int qt = 0; qt < 4; ++qt) {
    pa0[qt] = *(const bf16x8*)&P_lds[w][qt * 16 + lr][lg * 8];
    pa1[qt] = *(const bf16x8*)&P_lds[w][qt * 16 + lr][32 + lg * 8];
  }
  const unsigned short* vbase =
      XV + (size_t)lr * 131072 + (size_t)win * 64 + lg * 8;
  unsigned short* ystore =
      Y + (p_base + (size_t)(lg >> 1) * 128 + ((lg & 1) << 2)) * 512 + lr;

  bf16x8 v0p[2], v1p[2];
#pragma unroll
  for (int pp = 0; pp < 2; ++pp) {
    const unsigned short* vp = vbase + (size_t)pp * (16 * 131072);
    v0p[pp] = *(const bf16x8*)vp;
    v1p[pp] = *(const bf16x8*)(vp + 32);
  }
#pragma unroll
  for (int nt = 0; nt < 32; ++nt) {
    const int cb = nt & 1;
    f32x4 o[4];
    __builtin_amdgcn_s_setprio(1);
#pragma unroll
    for (int qt = 0; qt < 4; ++qt) {
      o[qt] = f32x4{0.f, 0.f, 0.f, 0.f};
      o[qt] = MFMA16(pa0[qt], v0p[cb], o[qt]);
      o[qt] = MFMA16(pa1[qt], v1p[cb], o[qt]);
    }
    __builtin_amdgcn_s_setprio(0);
    if (nt + 2 < 32) {
      const unsigned short* vp = vbase + (size_t)(nt + 2) * (16 * 131072);
      v0p[cb] = *(const bf16x8*)vp;
      v1p[cb] = *(const bf16x8*)(vp + 32);
    }
#pragma unroll
    for (int qt = 0; qt < 4; ++qt)
#pragma unroll
      for (int r = 0; r < 4; ++r)
        ystore[(size_t)qt * 131072 + r * 512 + nt * 16] = f2b(o[qt][r]);
  }
}

// ---------------- launch ----------------
extern "C" void kernel_launch(void* const* d_in, const int* in_sizes, int n_in,
                              void* d_out, int out_size, void* d_ws,
                              size_t ws_size, hipStream_t stream) {
  (void)in_sizes; (void)n_in; (void)out_size;
  const float* x = (const float*)d_in[0];
  const float* wq = (const float*)d_in[1];
  const float* bq = (const float*)d_in[2];
  const float* wk = (const float*)d_in[3];
  const float* bk = (const float*)d_in[4];  // cancels in softmax (exactly)
  const float* wv = (const float*)d_in[5];
  const float* bv = (const float*)d_in[6];
  const float* wo = (const float*)d_in[7];
  const float* bo = (const float*)d_in[8];
  (void)bk;

  const size_t NEED = (size_t)(2097152 + 3 * 67108864) * 2;
  if (ws_size < NEED) return;

  unsigned short* wb = (unsigned short*)d_ws;
  // [0]=wqT [262144]=wkT [524288]=wvT [786432]=wo_b [1048576]=wvo
  unsigned short* wvo = wb + 1048576;
  float* bvo = (float*)(wb + 1310720);
  float* ub = (float*)(wb + 1311744);
  unsigned short* Bqk = wb + 1572864;
  unsigned short* xT = wb + 2097152;    // [pixel][c]
  unsigned short* xV = xT + 67108864;   // [c][win*64+tok]
  unsigned short* Ybuf = xV + 67108864; // attn output
  unsigned short* Tq = (unsigned short*)d_out;  // T staged (bf16), fully
                                                // overwritten by MODE 2 fp32

  k_wprep<<<dim3(8, 8, 4), 256, 0, stream>>>(wq, wk, wv, wo, wb);
  k_bias<<<4, 256, 0, stream>>>(wo, bv, bo, wk, bq, bvo, ub);
  k_gemm256<4><<<8, 512, 0, stream>>>(wb, wb, nullptr, wb);  // Bqk + wvo
  k_transpose<<<dim3(32, 16, 8), 256, 0, stream>>>(x, xT, xV);
  k_gemm256<0><<<1024, 512, 0, stream>>>(xT, Bqk, ub, Tq);   // T = X*Bqk^T + u
  k_attn<<<512, 256, 0, stream>>>(Tq, xT, xV, Ybuf);
  k_gemm256<2><<<1024, 512, 0, stream>>>(Ybuf, wvo, bvo, d_out);
}

// Round 26
// 519.555 us; speedup vs baseline: 1.0168x; 1.0168x over previous
//
#include <hip/hip_runtime.h>

typedef __attribute__((ext_vector_type(8))) short bf16x8;
typedef __attribute__((ext_vector_type(4))) float f32x4;

#define MFMA16(a, b, c) __builtin_amdgcn_mfma_f32_16x16x32_bf16((a), (b), (c), 0, 0, 0)

__device__ __forceinline__ float b2f(unsigned short u) {
  unsigned int v = ((unsigned int)u) << 16;
  return __builtin_bit_cast(float, v);
}
__device__ __forceinline__ unsigned short f2b(float f) {
  unsigned int u = __builtin_bit_cast(unsigned int, f);
  u += 0x7fffu + ((u >> 16) & 1u);
  return (unsigned short)(u >> 16);
}
__device__ __forceinline__ void gload16(const void* g, void* l) {
  __builtin_amdgcn_global_load_lds(
      (const __attribute__((address_space(1))) unsigned int*)g,
      (__attribute__((address_space(3))) unsigned int*)l, 16, 0, 0);
}

// ------- weight prep: z=0..2: w fp32 [a][b] -> bf16 [b][a]; z=3: wo copy-convert -------
__global__ __launch_bounds__(256) void k_wprep(
    const float* __restrict__ wq, const float* __restrict__ wk,
    const float* __restrict__ wv, const float* __restrict__ wo,
    unsigned short* __restrict__ outbase) {
  const int z = blockIdx.z;
  const int t = threadIdx.x;
  if (z == 3) {  // wo -> outbase+786432, layout preserved
    const int r0 = blockIdx.x << 6, s0 = blockIdx.y << 6;
    const int row = r0 + (t >> 2), col = s0 + (t & 3) * 16;
    const float* src = wo + (size_t)row * 512 + col;
    unsigned short* dst = outbase + 786432 + (size_t)row * 512 + col;
    unsigned short o[16];
#pragma unroll
    for (int i = 0; i < 4; ++i) {
      const float4 v = ((const float4*)src)[i];
      o[i * 4 + 0] = f2b(v.x); o[i * 4 + 1] = f2b(v.y);
      o[i * 4 + 2] = f2b(v.z); o[i * 4 + 3] = f2b(v.w);
    }
    *(uint4*)dst = *(const uint4*)&o[0];
    *(uint4*)(dst + 8) = *(const uint4*)&o[8];
    return;
  }
  __shared__ unsigned short tile[64][72];
  const float* in = (z == 0) ? wq : (z == 1) ? wk : wv;
  unsigned short* out = outbase + (size_t)z * 262144u;
  const int r0 = blockIdx.x << 6, s0 = blockIdx.y << 6;
  {
    const int sl = t >> 3, rl = (t & 7) << 3;
#pragma unroll
    for (int pass = 0; pass < 2; ++pass) {
      const int s = sl + pass * 32;
      const float* src = in + (size_t)(s0 + s) * 512 + r0 + rl;
      const float4 f0 = ((const float4*)src)[0];
      const float4 f1 = ((const float4*)src)[1];
      tile[rl + 0][s] = f2b(f0.x);
      tile[rl + 1][s] = f2b(f0.y);
      tile[rl + 2][s] = f2b(f0.z);
      tile[rl + 3][s] = f2b(f0.w);
      tile[rl + 4][s] = f2b(f1.x);
      tile[rl + 5][s] = f2b(f1.y);
      tile[rl + 6][s] = f2b(f1.z);
      tile[rl + 7][s] = f2b(f1.w);
    }
  }
  __syncthreads();
  {
    const int rl = t >> 3, sl = (t & 7) << 3;
#pragma unroll
    for (int pass = 0; pass < 2; ++pass) {
      const int r = rl + pass * 32;
      uint4 v = *(const uint4*)&tile[r][sl];
      *(uint4*)(out + (size_t)(r0 + r) * 512 + s0 + sl) = v;
    }
  }
}

// ---- fused bias prep: blocks 0-1: bvo[o]=bo[o]+wo[o][:]*bv; blocks 2-3: u[c]=bq^T wk[:][c]
__global__ __launch_bounds__(256) void k_bias(
    const float* __restrict__ wo, const float* __restrict__ bv,
    const float* __restrict__ bo, const float* __restrict__ wk,
    const float* __restrict__ bq, float* __restrict__ bvo,
    float* __restrict__ u) {
  const int bid = blockIdx.x;
  if (bid < 2) {
    const int o = bid * 256 + threadIdx.x;
    float acc = bo[o];
    const float* row = wo + (size_t)o * 512;
    for (int j = 0; j < 512; ++j) acc += row[j] * bv[j];
    bvo[o] = acc;
  } else {
    const int c = (bid - 2) * 256 + threadIdx.x;
    float acc = 0.f;
    for (int o = 0; o < 512; ++o) acc += bq[o] * wk[(size_t)o * 512 + c];
    u[c] = acc;
  }
}

// ---- K0: transpose via global_load_lds (best of 6 variants; closed). ----
__global__ __launch_bounds__(256, 4) void k_transpose(
    const float* __restrict__ X, unsigned short* __restrict__ XT,
    unsigned short* __restrict__ XV) {
  __shared__ float lds[2][8 * 516];
  const int hz = blockIdx.x;
  const int cgB = blockIdx.y;
  const int b = blockIdx.z;
  const int h0 = hz << 2;
  const int c0 = cgB << 5;
  const int t = threadIdx.x;
  const float* xb = X + (size_t)b * 8388608u + (size_t)h0 * 128;

  auto stage = [&](int s) {
    float* dstb = lds[s & 1];
#pragma unroll
    for (int i = 0; i < 4; ++i) {
      const int q4 = i * 256 + t;
      const int cl = q4 >> 7;
      const int q = q4 & 127;
      gload16(xb + (size_t)(c0 + s * 8 + cl) * 16384 + q * 4,
              dstb + (size_t)cl * 516 + q * 4);
    }
  };

  unsigned short xo[2][32];

  stage(0);
#pragma unroll
  for (int s = 0; s < 4; ++s) {
    if (s < 3) {
      stage(s + 1);
      asm volatile("s_waitcnt vmcnt(4)" ::: "memory");
    } else {
      asm volatile("s_waitcnt vmcnt(0)" ::: "memory");
    }
    __builtin_amdgcn_s_barrier();
    const float* L = lds[s & 1];
#pragma unroll
    for (int pp = 0; pp < 2; ++pp) {
      const int p = t + pp * 256;
#pragma unroll
      for (int cl = 0; cl < 8; ++cl)
        xo[pp][s * 8 + cl] = f2b(L[cl * 516 + p]);
    }
    {
      const int cl = t >> 5, win = t & 15, hb = (t >> 4) & 1;
      const int wing = b * 256 + (h0 >> 3) * 16 + win;
      const int tok0 = (h0 & 4) * 8;
      unsigned short* dvb =
          XV + (size_t)(c0 + s * 8 + cl) * 131072 + (size_t)wing * 64 + tok0;
#pragma unroll
      for (int k = 0; k < 2; ++k) {
        const int hr = hb + k * 2;
        const float* src = &L[cl * 516 + hr * 128 + win * 8];
        unsigned short ov[8];
#pragma unroll
        for (int j = 0; j < 8; ++j) ov[j] = f2b(src[j]);
        *(uint4*)(dvb + hr * 8) = *(const uint4*)ov;
      }
    }
    __builtin_amdgcn_s_barrier();
  }

#pragma unroll
  for (int pp = 0; pp < 2; ++pp) {
    const int p = t + pp * 256;
    unsigned short* d =
        XT + ((size_t)b * 16384 + (size_t)h0 * 128 + p) * 512 + c0;
    *(uint4*)(d + 0) = *(const uint4*)&xo[pp][0];
    *(uint4*)(d + 8) = *(const uint4*)&xo[pp][8];
    *(uint4*)(d + 16) = *(const uint4*)&xo[pp][16];
    *(uint4*)(d + 24) = *(const uint4*)&xo[pp][24];
  }
}

// ==== 256x256 GEMM, 16 K-subtiles of 32, 4-buffer depth-3 counted pipeline + swizzle
// (best-measured configuration, benched 522.5us at R21).
// MODE 0: T-proj. bf16 C[m=pixel][n] ldc=512, bias0[n]. grid 1024 XCD-chunked.
// MODE 2: final.  A=wvo, B=Y. fp32 C->(B,C,H,W) from [m=chan][n=pixel], bias0[m].
//         grid 1024, NT scalar stores.
// MODE 4: fused weight-prep (grid 8).
template <int MODE>
__global__ __launch_bounds__(512, 2) void k_gemm256(
    const unsigned short* __restrict__ A, const unsigned short* __restrict__ B,
    const float* __restrict__ bias0, void* __restrict__ C0v) {
  __shared__ unsigned short lsA[4][256 * 32];
  __shared__ unsigned short lsB[4][256 * 32];
  const int bid = blockIdx.x;
  int mt, nt, sel = 0;
  if (MODE == 0) {
    const int work = ((bid & 7) << 7) + (bid >> 3);  // grid 1024
    mt = work >> 1; nt = work & 1;
  } else if (MODE == 2) {
    const int work = ((bid & 7) << 7) + (bid >> 3);  // grid 1024
    nt = work >> 1; mt = work & 1;
  } else {  // MODE 4
    sel = bid >> 2;
    mt = bid & 1; nt = (bid >> 1) & 1;
  }
  const unsigned short* Ap = A;
  const unsigned short* Bp = B;
  if (MODE == 4) {
    Ap = sel ? A + 786432 : A + 262144;  // wo_b : wkT
    Bp = sel ? A + 524288 : A;           // wvT  : wqT
  }
  const int m0 = mt << 8, n0 = nt << 8;

  const int t = threadIdx.x;
  const int l = t & 63;
  const int lr = l & 15, lg = l >> 4;
  const int w = t >> 6;
  const int wr = w >> 2, wc = w & 3;
  const int ra = wr << 7, rb = wc << 6;
  const int srowS = t >> 2;            // 0..127 (+128 for 2nd gload)
  const int scolS = (t & 3) << 3;      // shorts
  const int ssw = ((srowS >> 1) & 3) << 3;   // stage-side inverse swizzle
  const int scolX = scolS ^ ssw;             // swizzled global column
  const int rsw = (lr >> 1) & 3;             // read-side swizzle
  const int rco = (lg ^ rsw) * 8;            // read column offset (shorts)

  f32x4 acc[8][4];
#pragma unroll
  for (int i = 0; i < 8; ++i)
#pragma unroll
    for (int j = 0; j < 4; ++j) acc[i][j] = f32x4{0.f, 0.f, 0.f, 0.f};

  auto stage = [&](int kt) {
    const int buf = kt & 3, k0 = kt << 5;
#pragma unroll
    for (int hh = 0; hh < 2; ++hh) {
      gload16(Ap + (size_t)(m0 + srowS + hh * 128) * 512 + k0 + scolX,
              &lsA[buf][(srowS + hh * 128) * 32 + scolS]);
      gload16(Bp + (size_t)(n0 + srowS + hh * 128) * 512 + k0 + scolX,
              &lsB[buf][(srowS + hh * 128) * 32 + scolS]);
    }
  };
  auto compute = [&](int kt) {
    const int buf = kt & 3;
    bf16x8 af[8], bfv[4];
#pragma unroll
    for (int i = 0; i < 8; ++i)
      af[i] = *(const bf16x8*)&lsA[buf][(ra + i * 16 + lr) * 32 + rco];
#pragma unroll
    for (int j = 0; j < 4; ++j)
      bfv[j] = *(const bf16x8*)&lsB[buf][(rb + j * 16 + lr) * 32 + rco];
    __builtin_amdgcn_s_setprio(1);
#pragma unroll
    for (int i = 0; i < 8; ++i)
#pragma unroll
      for (int j = 0; j < 4; ++j)
        acc[i][j] = MFMA16(af[i], bfv[j], acc[i][j]);
    __builtin_amdgcn_s_setprio(0);
  };

  stage(0); stage(1); stage(2);  // depth-3 prologue

#define GITER(kt, vm)                                        \
  asm volatile("s_waitcnt vmcnt(" #vm ")" ::: "memory");     \
  __builtin_amdgcn_s_barrier();                              \
  __builtin_amdgcn_sched_barrier(0);                         \
  if ((kt) + 3 < 16) stage((kt) + 3);                        \
  compute(kt);                                               \
  __builtin_amdgcn_sched_barrier(0);                         \
  __builtin_amdgcn_s_barrier();

  GITER(0, 8)  GITER(1, 8)  GITER(2, 8)  GITER(3, 8)
  GITER(4, 8)  GITER(5, 8)  GITER(6, 8)  GITER(7, 8)
  GITER(8, 8)  GITER(9, 8)  GITER(10, 8) GITER(11, 8)
  GITER(12, 8) GITER(13, 8) GITER(14, 4) GITER(15, 0)
#undef GITER

  // ---------------- epilogue ----------------
#pragma unroll
  for (int i = 0; i < 8; ++i) {
    const int cmb = m0 + ra + i * 16 + lg * 4;
#pragma unroll
    for (int j = 0; j < 4; ++j) {
      const int cn = n0 + rb + j * 16 + lr;
      const float bn = (MODE == 0) ? bias0[cn] : 0.f;
#pragma unroll
      for (int r = 0; r < 4; ++r) {
        const int cm = cmb + r;
        if (MODE == 0) {
          ((unsigned short*)C0v)[(size_t)cm * 512 + cn] = f2b(acc[i][j][r] + bn);
        } else if (MODE == 2) {
          const float val = acc[i][j][r] + bias0[cm];
          const int bb = cn >> 14, p = cn & 16383;
          __builtin_nontemporal_store(
              val, (float*)C0v + (size_t)bb * 8388608 + (size_t)cm * 16384 + p);
        } else {
          unsigned short* Cs =
              (unsigned short*)C0v + (sel ? 1048576 : 1572864);
          Cs[(size_t)cm * 512 + cn] = f2b(acc[i][j][r]);
        }
      }
    }
  }
}

// ---------------- K2: window attention, ONE WAVE PER WINDOW (unchanged) ----------------
__global__ __launch_bounds__(256) void k_attn(
    const unsigned short* __restrict__ Q, const unsigned short* __restrict__ XT,
    const unsigned short* __restrict__ XV, unsigned short* __restrict__ Y) {
  __shared__ unsigned short P_lds[4][64][72];
  const int t = threadIdx.x, w = t >> 6, l = t & 63;
  const int lr = l & 15, lg = l >> 4;
  const int grp = ((blockIdx.x & 7) << 6) + (blockIdx.x >> 3);  // 0..511
  const int win = grp * 4 + w;
  const int b = win >> 8, th = (win >> 4) & 15, tw = win & 15;
  const size_t p_base = (size_t)b * 16384 + (size_t)th * 1024 + (size_t)tw * 8;
  const size_t rowpix = p_base + (size_t)(lr >> 3) * 128 + (lr & 7);
  const unsigned short* qbase = Q + rowpix * 512;
  const unsigned short* kbase = XT + rowpix * 512;

  f32x4 acc[4][4];
#pragma unroll
  for (int i = 0; i < 4; ++i)
#pragma unroll
    for (int j = 0; j < 4; ++j) acc[i][j] = f32x4{0.f, 0.f, 0.f, 0.f};

  bf16x8 kp[2][4], qp[2][4];
#pragma unroll
  for (int pp = 0; pp < 2; ++pp) {
    const int co = pp * 32 + lg * 8;
#pragma unroll
    for (int i = 0; i < 4; ++i) {
      kp[pp][i] = *(const bf16x8*)(kbase + (size_t)i * 131072 + co);
      qp[pp][i] = *(const bf16x8*)(qbase + (size_t)i * 131072 + co);
    }
  }
#pragma unroll
  for (int cs = 0; cs < 16; ++cs) {
    const int cb = cs & 1;
    __builtin_amdgcn_s_setprio(1);
#pragma unroll
    for (int mt = 0; mt < 4; ++mt)
#pragma unroll
      for (int qt = 0; qt < 4; ++qt)
        acc[mt][qt] = MFMA16(kp[cb][mt], qp[cb][qt], acc[mt][qt]);
    __builtin_amdgcn_s_setprio(0);
    if (cs + 2 < 16) {
      const int co = (cs + 2) * 32 + lg * 8;
#pragma unroll
      for (int i = 0; i < 4; ++i) {
        kp[cb][i] = *(const bf16x8*)(kbase + (size_t)i * 131072 + co);
        qp[cb][i] = *(const bf16x8*)(qbase + (size_t)i * 131072 + co);
      }
    }
  }

  const float scale = 0.044194173824159216f;  // 1/sqrt(512)
#pragma unroll
  for (int qt = 0; qt < 4; ++qt) {
    float pv[4][4];
    float mx = -3.0e38f;
#pragma unroll
    for (int mt = 0; mt < 4; ++mt)
#pragma unroll
      for (int j = 0; j < 4; ++j) {
        const float s = acc[mt][qt][j] * scale;
        pv[mt][j] = s;
        mx = fmaxf(mx, s);
      }
    mx = fmaxf(mx, __shfl_xor(mx, 16));
    mx = fmaxf(mx, __shfl_xor(mx, 32));
    float sum = 0.f;
#pragma unroll
    for (int mt = 0; mt < 4; ++mt)
#pragma unroll
      for (int j = 0; j < 4; ++j) {
        const float e = __expf(pv[mt][j] - mx);
        pv[mt][j] = e;
        sum += e;
      }
    sum += __shfl_xor(sum, 16);
    sum += __shfl_xor(sum, 32);
    const float inv = 1.f / sum;
#pragma unroll
    for (int mt = 0; mt < 4; ++mt)
#pragma unroll
      for (int j = 0; j < 4; j += 2) {
        const unsigned int pk =
            (unsigned int)f2b(pv[mt][j] * inv) |
            ((unsigned int)f2b(pv[mt][j + 1] * inv) << 16);
        *(unsigned int*)&P_lds[w][qt * 16 + lr][mt * 16 + lg * 4 + j] = pk;
      }
  }

  bf16x8 pa0[4], pa1[4];
#pragma unroll
  for (int qt = 0; qt < 4; ++qt) {
    pa0[qt] = *(const bf16x8*)&P_lds[w][qt * 16 + lr][lg * 8];
    pa1[qt] = *(const bf16x8*)&P_lds[w][qt * 16 + lr][32 + lg * 8];
  }
  const unsigned short* vbase =
      XV + (size_t)lr * 131072 + (size_t)win * 64 + lg * 8;
  unsigned short* ystore =
      Y + (p_base + (size_t)(lg >> 1) * 128 + ((lg & 1) << 2)) * 512 + lr;

  bf16x8 v0p[2], v1p[2];
#pragma unroll
  for (int pp = 0; pp < 2; ++pp) {
    const unsigned short* vp = vbase + (size_t)pp * (16 * 131072);
    v0p[pp] = *(const bf16x8*)vp;
    v1p[pp] = *(const bf16x8*)(vp + 32);
  }
#pragma unroll
  for (int nt = 0; nt < 32; ++nt) {
    const int cb = nt & 1;
    f32x4 o[4];
    __builtin_amdgcn_s_setprio(1);
#pragma unroll
    for (int qt = 0; qt < 4; ++qt) {
      o[qt] = f32x4{0.f, 0.f, 0.f, 0.f};
      o[qt] = MFMA16(pa0[qt], v0p[cb], o[qt]);
      o[qt] = MFMA16(pa1[qt], v1p[cb], o[qt]);
    }
    __builtin_amdgcn_s_setprio(0);
    if (nt + 2 < 32) {
      const unsigned short* vp = vbase + (size_t)(nt + 2) * (16 * 131072);
      v0p[cb] = *(const bf16x8*)vp;
      v1p[cb] = *(const bf16x8*)(vp + 32);
    }
#pragma unroll
    for (int qt = 0; qt < 4; ++qt)
#pragma unroll
      for (int r = 0; r < 4; ++r)
        ystore[(size_t)qt * 131072 + r * 512 + nt * 16] = f2b(o[qt][r]);
  }
}

// ---------------- launch ----------------
extern "C" void kernel_launch(void* const* d_in, const int* in_sizes, int n_in,
                              void* d_out, int out_size, void* d_ws,
                              size_t ws_size, hipStream_t stream) {
  (void)in_sizes; (void)n_in; (void)out_size;
  const float* x = (const float*)d_in[0];
  const float* wq = (const float*)d_in[1];
  const float* bq = (const float*)d_in[2];
  const float* wk = (const float*)d_in[3];
  const float* bk = (const float*)d_in[4];  // cancels in softmax (exactly)
  const float* wv = (const float*)d_in[5];
  const float* bv = (const float*)d_in[6];
  const float* wo = (const float*)d_in[7];
  const float* bo = (const float*)d_in[8];
  (void)bk;

  const size_t NEED = (size_t)(2097152 + 3 * 67108864) * 2;
  if (ws_size < NEED) return;

  unsigned short* wb = (unsigned short*)d_ws;
  // [0]=wqT [262144]=wkT [524288]=wvT [786432]=wo_b [1048576]=wvo
  unsigned short* wvo = wb + 1048576;
  float* bvo = (float*)(wb + 1310720);
  float* ub = (float*)(wb + 1311744);
  unsigned short* Bqk = wb + 1572864;
  unsigned short* xT = wb + 2097152;    // [pixel][c]
  unsigned short* xV = xT + 67108864;   // [c][win*64+tok]
  unsigned short* Ybuf = xV + 67108864; // attn output
  unsigned short* Tq = (unsigned short*)d_out;  // T staged (bf16), fully
                                                // overwritten by MODE 2 fp32

  k_wprep<<<dim3(8, 8, 4), 256, 0, stream>>>(wq, wk, wv, wo, wb);
  k_bias<<<4, 256, 0, stream>>>(wo, bv, bo, wk, bq, bvo, ub);
  k_gemm256<4><<<8, 512, 0, stream>>>(wb, wb, nullptr, wb);  // Bqk + wvo
  k_transpose<<<dim3(32, 16, 8), 256, 0, stream>>>(x, xT, xV);
  k_gemm256<0><<<1024, 512, 0, stream>>>(xT, Bqk, ub, Tq);   // T = X*Bqk^T + u
  k_attn<<<512, 256, 0, stream>>>(Tq, xT, xV, Ybuf);
  k_gemm256<2><<<1024, 512, 0, stream>>>(wvo, Ybuf, bvo, d_out);
}